// Round 1
// baseline (1362.902 us; speedup 1.0000x reference)
//
#include <hip/hip_runtime.h>

#define NODES 50000
#define RELS  3
#define NEDGE 600000
#define FIN   128
#define FHID  64
#define FOUT  64

// ---------------- degree accumulation (shared by both layers) ----------------
__global__ __launch_bounds__(256) void deg_kernel(const int* __restrict__ src,
                                                  const int* __restrict__ dst,
                                                  float* __restrict__ outdeg,
                                                  float* __restrict__ indeg) {
    int i = blockIdx.x * 256 + threadIdx.x;   // over RELS*NEDGE
    if (i >= RELS * NEDGE) return;
    int r = i / NEDGE;
    int s = src[i];
    int d = dst[i];
    unsafeAtomicAdd(&outdeg[r * NODES + s], 1.0f);
    unsafeAtomicAdd(&indeg[r * NODES + d], 1.0f);
}

// deg -> 1/sqrt(max(deg,1)), in place over 2*RELS*NODES contiguous floats
__global__ __launch_bounds__(256) void norm_kernel(float* __restrict__ deg) {
    int i = blockIdx.x * 256 + threadIdx.x;
    if (i >= 2 * RELS * NODES) return;
    deg[i] = 1.0f / sqrtf(fmaxf(deg[i], 1.0f));
}

// ---------------- layer 1 GEMM: h[r][n][j] = (x[n,:] . W1[r][:,j]) * outnorm[r][n]
__global__ __launch_bounds__(256) void gemm1_kernel(const float* __restrict__ x,
                                                    const float* __restrict__ W1,
                                                    const float* __restrict__ outnorm,
                                                    float* __restrict__ h) {
    __shared__ float Wl[FIN * FHID];          // 32 KB
    int r = blockIdx.y;
    const float* Wr = W1 + r * FIN * FHID;
    for (int t = threadIdx.x; t < FIN * FHID; t += 256) Wl[t] = Wr[t];
    __syncthreads();
    int j  = threadIdx.x & 63;
    int ln = threadIdx.x >> 6;
    int n  = blockIdx.x * 4 + ln;             // NODES % 4 == 0
    const float* xr = x + n * FIN;
    float acc = 0.f;
#pragma unroll 8
    for (int k = 0; k < FIN; ++k) acc = fmaf(xr[k], Wl[k * FHID + j], acc);
    h[(r * NODES + n) * FHID + j] = acc * outnorm[r * NODES + n];
}

// ---------------- layer 1 scatter: B[d][j] += h[r][s][j] * innorm[r][d] (all rels merged)
__global__ __launch_bounds__(256) void scatter1_kernel(const float* __restrict__ h,
                                                       const int* __restrict__ src,
                                                       const int* __restrict__ dst,
                                                       const float* __restrict__ innorm,
                                                       float* __restrict__ agg) {
    int r = blockIdx.y;
    int e = blockIdx.x * 4 + (threadIdx.x >> 6);   // NEDGE % 4 == 0
    int j = threadIdx.x & 63;
    int s = src[r * NEDGE + e];
    int d = dst[r * NEDGE + e];
    float v = h[(r * NODES + s) * FHID + j] * innorm[r * NODES + d];
    unsafeAtomicAdd(&agg[d * FHID + j], v);
}

// ---------------- layer 1 epilogue: h1 = relu(agg + sum_r b1[r]) in place
__global__ __launch_bounds__(256) void combine1_kernel(float* __restrict__ hb,
                                                       const float* __restrict__ b1) {
    int i = blockIdx.x * 256 + threadIdx.x;   // NODES*FHID, exact multiple of 256
    int j = i & 63;
    float bs = b1[j] + b1[FHID + j] + b1[2 * FHID + j];
    hb[i] = fmaxf(hb[i] + bs, 0.f);
}

// ---------------- layer 2 scatter: A[r][d][j] += h1[s][j]*outnorm[r][s]*innorm[r][d]
__global__ __launch_bounds__(256) void scatter2_kernel(const float* __restrict__ h1,
                                                       const int* __restrict__ src,
                                                       const int* __restrict__ dst,
                                                       const float* __restrict__ outnorm,
                                                       const float* __restrict__ innorm,
                                                       float* __restrict__ agg2) {
    int r = blockIdx.y;
    int e = blockIdx.x * 4 + (threadIdx.x >> 6);
    int j = threadIdx.x & 63;
    int s = src[r * NEDGE + e];
    int d = dst[r * NEDGE + e];
    float v = h1[s * FHID + j] * outnorm[r * NODES + s] * innorm[r * NODES + d];
    unsafeAtomicAdd(&agg2[(r * NODES + d) * FHID + j], v);
}

// ---------------- layer 2 GEMM + combine: out[n][j] = sum_r A[r][n,:] . W2[r][:,j] + sum_r b2[r][j]
// (innorm already folded into A during scatter2: (D S) W == D (S W))
__global__ __launch_bounds__(256) void out_kernel(const float* __restrict__ agg2,
                                                  const float* __restrict__ W2,
                                                  const float* __restrict__ b2,
                                                  float* __restrict__ out) {
    __shared__ float Wl[RELS * FHID * FOUT];  // 48 KB
    for (int t = threadIdx.x; t < RELS * FHID * FOUT; t += 256) Wl[t] = W2[t];
    __syncthreads();
    int j  = threadIdx.x & 63;
    int ln = threadIdx.x >> 6;
    int n  = blockIdx.x * 4 + ln;
    float acc = b2[j] + b2[FOUT + j] + b2[2 * FOUT + j];
#pragma unroll
    for (int r = 0; r < RELS; ++r) {
        const float* a = agg2 + (r * NODES + n) * FHID;
        const float* w = Wl + r * FHID * FOUT;
        float s = 0.f;
#pragma unroll 8
        for (int k = 0; k < FHID; ++k) s = fmaf(a[k], w[k * FOUT + j], s);
        acc += s;
    }
    out[n * FOUT + j] = acc;
}

extern "C" void kernel_launch(void* const* d_in, const int* in_sizes, int n_in,
                              void* d_out, int out_size, void* d_ws, size_t ws_size,
                              hipStream_t stream) {
    const float* x   = (const float*)d_in[0];   // [N,128]
    const float* W1  = (const float*)d_in[1];   // [3,128,64]
    const float* b1  = (const float*)d_in[2];   // [3,64]
    const float* W2  = (const float*)d_in[3];   // [3,64,64]
    const float* b2  = (const float*)d_in[4];   // [3,64]
    const int*   src = (const int*)d_in[5];     // [3,E]
    const int*   dst = (const int*)d_in[6];     // [3,E]
    float* out = (float*)d_out;                 // [N,64]

    // workspace layout (floats): outnorm[3N] | innorm[3N] | A[3*N*64] | B[N*64]
    float* outnorm = (float*)d_ws;
    float* innorm  = outnorm + RELS * NODES;
    float* A       = innorm + RELS * NODES;           // layer-1 h, reused as layer-2 agg
    float* B       = A + (size_t)RELS * NODES * FHID; // layer-1 agg / h1
    // total: 6*N + 4*N*64 floats = 52.4 MB

    // degrees -> norms (shared by both layers)
    hipMemsetAsync(outnorm, 0, 2ull * RELS * NODES * sizeof(float), stream);
    deg_kernel<<<(RELS * NEDGE + 255) / 256, 256, 0, stream>>>(src, dst, outnorm, innorm);
    norm_kernel<<<(2 * RELS * NODES + 255) / 256, 256, 0, stream>>>(outnorm);

    // layer 1
    gemm1_kernel<<<dim3(NODES / 4, RELS), 256, 0, stream>>>(x, W1, outnorm, A);
    hipMemsetAsync(B, 0, (size_t)NODES * FHID * sizeof(float), stream);
    scatter1_kernel<<<dim3(NEDGE / 4, RELS), 256, 0, stream>>>(A, src, dst, innorm, B);
    combine1_kernel<<<NODES * FHID / 256, 256, 0, stream>>>(B, b1);

    // layer 2
    hipMemsetAsync(A, 0, (size_t)RELS * NODES * FHID * sizeof(float), stream);
    scatter2_kernel<<<dim3(NEDGE / 4, RELS), 256, 0, stream>>>(B, src, dst, outnorm, innorm, A);
    out_kernel<<<NODES / 4, 256, 0, stream>>>(A, W2, b2, out);
}

// Round 2
// 732.704 us; speedup vs baseline: 1.8601x; 1.8601x over previous
//
#include <hip/hip_runtime.h>

#define NODES 50000
#define RELS  3
#define NEDGE 600000
#define FIN   128
#define FHID  64
#define FOUT  64
#define SEGS  (RELS * NODES)            // 150000 (rel, dst) segments
#define NBLK  ((SEGS + 255) / 256)      // 586 scan blocks

// ---------------- degree counting (int) ----------------
__global__ __launch_bounds__(256) void deg_kernel(const int* __restrict__ src,
                                                  const int* __restrict__ dst,
                                                  int* __restrict__ odI,
                                                  int* __restrict__ idI) {
    int e = blockIdx.x * 256 + threadIdx.x;
    int r = blockIdx.y;
    if (e >= NEDGE) return;
    atomicAdd(&odI[r * NODES + src[r * NEDGE + e]], 1);
    atomicAdd(&idI[r * NODES + dst[r * NEDGE + e]], 1);
}

// ---------------- norms from int degrees ----------------
__global__ __launch_bounds__(256) void norm_kernel(const int* __restrict__ odI,
                                                   const int* __restrict__ idI,
                                                   float* __restrict__ outnorm,
                                                   float* __restrict__ innorm) {
    int i = blockIdx.x * 256 + threadIdx.x;
    if (i >= SEGS) return;
    outnorm[i] = 1.0f / sqrtf(fmaxf((float)odI[i], 1.0f));
    innorm[i]  = 1.0f / sqrtf(fmaxf((float)idI[i], 1.0f));
}

// ---------------- exclusive scan over idI (3 kernels) ----------------
__global__ __launch_bounds__(256) void scan_sums_kernel(const int* __restrict__ idI,
                                                        int* __restrict__ partials) {
    __shared__ int s[256];
    int i = blockIdx.x * 256 + threadIdx.x;
    s[threadIdx.x] = (i < SEGS) ? idI[i] : 0;
    __syncthreads();
    for (int off = 128; off > 0; off >>= 1) {
        if (threadIdx.x < off) s[threadIdx.x] += s[threadIdx.x + off];
        __syncthreads();
    }
    if (threadIdx.x == 0) partials[blockIdx.x] = s[0];
}

__global__ __launch_bounds__(1024) void scan_partials_kernel(int* __restrict__ partials) {
    __shared__ int s[1024];
    int tid = threadIdx.x;
    int v = (tid < NBLK) ? partials[tid] : 0;
    s[tid] = v;
    __syncthreads();
    for (int off = 1; off < 1024; off <<= 1) {
        int t = s[tid];
        int add = (tid >= off) ? s[tid - off] : 0;
        __syncthreads();
        s[tid] = t + add;
        __syncthreads();
    }
    if (tid < NBLK) partials[tid] = s[tid] - v;   // exclusive
}

__global__ __launch_bounds__(256) void scan_write_kernel(const int* __restrict__ idI,
                                                         const int* __restrict__ partials,
                                                         int* __restrict__ offs) {
    __shared__ int s[256];
    int tid = threadIdx.x;
    int i = blockIdx.x * 256 + tid;
    int v = (i < SEGS) ? idI[i] : 0;
    s[tid] = v;
    __syncthreads();
    for (int off = 1; off < 256; off <<= 1) {
        int t = s[tid];
        int add = (tid >= off) ? s[tid - off] : 0;
        __syncthreads();
        s[tid] = t + add;
        __syncthreads();
    }
    if (i < SEGS) offs[i] = partials[blockIdx.x] + (s[tid] - v);
}

// ---------------- CSR fill: bucket src ids by (rel,dst) ----------------
__global__ __launch_bounds__(256) void fill_kernel(const int* __restrict__ src,
                                                   const int* __restrict__ dst,
                                                   const int* __restrict__ offs,
                                                   int* __restrict__ cursor,
                                                   int* __restrict__ edge_src) {
    int e = blockIdx.x * 256 + threadIdx.x;
    int r = blockIdx.y;
    if (e >= NEDGE) return;
    int seg = r * NODES + dst[r * NEDGE + e];
    int pos = offs[seg] + atomicAdd(&cursor[seg], 1);
    edge_src[pos] = src[r * NEDGE + e];
}

// ---------------- layer 1 GEMM: h[r][n][j] = (x[n,:].W1[r][:,j]) * outnorm[r][n]
// 2 rows per thread, float4 x loads.
__global__ __launch_bounds__(256) void gemm1_kernel(const float* __restrict__ x,
                                                    const float* __restrict__ W1,
                                                    const float* __restrict__ outnorm,
                                                    float* __restrict__ h) {
    __shared__ float Wl[FIN * FHID];          // 32 KB
    int r = blockIdx.y;
    const float* Wr = W1 + r * FIN * FHID;
    for (int t = threadIdx.x; t < FIN * FHID; t += 256) Wl[t] = Wr[t];
    __syncthreads();
    int j  = threadIdx.x & 63;
    int g  = threadIdx.x >> 6;
    int n0 = blockIdx.x * 8 + g * 2;          // NODES % 8 == 0
    const float4* x0 = (const float4*)(x + (size_t)n0 * FIN);
    const float4* x1 = (const float4*)(x + (size_t)(n0 + 1) * FIN);
    float acc0 = 0.f, acc1 = 0.f;
#pragma unroll 4
    for (int k4 = 0; k4 < FIN / 4; ++k4) {
        float4 a0 = x0[k4], a1 = x1[k4];
        const float* w = Wl + k4 * 4 * FHID + j;
        acc0 = fmaf(a0.x, w[0], acc0);          acc1 = fmaf(a1.x, w[0], acc1);
        acc0 = fmaf(a0.y, w[FHID], acc0);       acc1 = fmaf(a1.y, w[FHID], acc1);
        acc0 = fmaf(a0.z, w[2 * FHID], acc0);   acc1 = fmaf(a1.z, w[2 * FHID], acc1);
        acc0 = fmaf(a0.w, w[3 * FHID], acc0);   acc1 = fmaf(a1.w, w[3 * FHID], acc1);
    }
    h[((size_t)r * NODES + n0) * FHID + j]     = acc0 * outnorm[r * NODES + n0];
    h[((size_t)r * NODES + n0 + 1) * FHID + j] = acc1 * outnorm[r * NODES + n0 + 1];
}

// ---------------- layer 1 gather: B[d][j] = relu(sum_r innorm[r][d]*sum_e h[r][src][j] + sum_r b1[r][j])
__global__ __launch_bounds__(256) void gather1_kernel(const float* __restrict__ h,
                                                      const int* __restrict__ es,
                                                      const int* __restrict__ offs,
                                                      const int* __restrict__ cnt,
                                                      const float* __restrict__ innorm,
                                                      const float* __restrict__ b1,
                                                      float* __restrict__ B) {
    int d = blockIdx.x * 4 + (threadIdx.x >> 6);   // NODES % 4 == 0
    int j = threadIdx.x & 63;
    float acc = 0.f;
#pragma unroll
    for (int r = 0; r < RELS; ++r) {
        int seg = r * NODES + d;
        int o = offs[seg], c = cnt[seg];
        const float* Ar = h + (size_t)r * NODES * FHID;
        float a0 = 0.f, a1 = 0.f, a2 = 0.f, a3 = 0.f;
        int t = 0;
        for (; t + 4 <= c; t += 4) {
            int i0 = es[o + t], i1 = es[o + t + 1], i2 = es[o + t + 2], i3 = es[o + t + 3];
            a0 += Ar[(size_t)i0 * FHID + j];
            a1 += Ar[(size_t)i1 * FHID + j];
            a2 += Ar[(size_t)i2 * FHID + j];
            a3 += Ar[(size_t)i3 * FHID + j];
        }
        for (; t < c; ++t) a0 += Ar[(size_t)es[o + t] * FHID + j];
        acc += innorm[seg] * ((a0 + a1) + (a2 + a3));
    }
    float bs = b1[j] + b1[FHID + j] + b1[2 * FHID + j];
    B[(size_t)d * FHID + j] = fmaxf(acc + bs, 0.f);
}

// ---------------- layer 2 gather: A[r][d][j] = innorm[r][d]*sum_e outnorm[r][src]*h1[src][j]
__global__ __launch_bounds__(256) void gather2_kernel(const float* __restrict__ h1,
                                                      const int* __restrict__ es,
                                                      const int* __restrict__ offs,
                                                      const int* __restrict__ cnt,
                                                      const float* __restrict__ outnorm,
                                                      const float* __restrict__ innorm,
                                                      float* __restrict__ A) {
    int d = blockIdx.x * 4 + (threadIdx.x >> 6);
    int r = blockIdx.y;
    int j = threadIdx.x & 63;
    int seg = r * NODES + d;
    int o = offs[seg], c = cnt[seg];
    const float* on = outnorm + r * NODES;
    float a0 = 0.f, a1 = 0.f, a2 = 0.f, a3 = 0.f;
    int t = 0;
    for (; t + 4 <= c; t += 4) {
        int i0 = es[o + t], i1 = es[o + t + 1], i2 = es[o + t + 2], i3 = es[o + t + 3];
        float w0 = on[i0], w1 = on[i1], w2 = on[i2], w3 = on[i3];
        a0 = fmaf(w0, h1[(size_t)i0 * FHID + j], a0);
        a1 = fmaf(w1, h1[(size_t)i1 * FHID + j], a1);
        a2 = fmaf(w2, h1[(size_t)i2 * FHID + j], a2);
        a3 = fmaf(w3, h1[(size_t)i3 * FHID + j], a3);
    }
    for (; t < c; ++t) {
        int i0 = es[o + t];
        a0 = fmaf(on[i0], h1[(size_t)i0 * FHID + j], a0);
    }
    A[(size_t)seg * FHID + j] = innorm[seg] * ((a0 + a1) + (a2 + a3));
}

// ---------------- layer 2 GEMM + combine: out = sum_r A[r] @ W2[r] + sum_r b2[r]
__global__ __launch_bounds__(256) void out_kernel(const float* __restrict__ agg2,
                                                  const float* __restrict__ W2,
                                                  const float* __restrict__ b2,
                                                  float* __restrict__ out) {
    __shared__ float Wl[RELS * FHID * FOUT];  // 48 KB
    for (int t = threadIdx.x; t < RELS * FHID * FOUT; t += 256) Wl[t] = W2[t];
    __syncthreads();
    int j  = threadIdx.x & 63;
    int g  = threadIdx.x >> 6;
    int n0 = blockIdx.x * 8 + g * 2;
    float acc0 = b2[j] + b2[FOUT + j] + b2[2 * FOUT + j];
    float acc1 = acc0;
#pragma unroll
    for (int r = 0; r < RELS; ++r) {
        const float4* a0 = (const float4*)(agg2 + ((size_t)r * NODES + n0) * FHID);
        const float4* a1 = (const float4*)(agg2 + ((size_t)r * NODES + n0 + 1) * FHID);
        const float* wr = Wl + r * FHID * FOUT;
#pragma unroll 4
        for (int k4 = 0; k4 < FHID / 4; ++k4) {
            float4 v0 = a0[k4], v1 = a1[k4];
            const float* w = wr + k4 * 4 * FOUT + j;
            acc0 = fmaf(v0.x, w[0], acc0);          acc1 = fmaf(v1.x, w[0], acc1);
            acc0 = fmaf(v0.y, w[FOUT], acc0);       acc1 = fmaf(v1.y, w[FOUT], acc1);
            acc0 = fmaf(v0.z, w[2 * FOUT], acc0);   acc1 = fmaf(v1.z, w[2 * FOUT], acc1);
            acc0 = fmaf(v0.w, w[3 * FOUT], acc0);   acc1 = fmaf(v1.w, w[3 * FOUT], acc1);
        }
    }
    out[(size_t)n0 * FOUT + j]       = acc0;
    out[(size_t)(n0 + 1) * FOUT + j] = acc1;
}

extern "C" void kernel_launch(void* const* d_in, const int* in_sizes, int n_in,
                              void* d_out, int out_size, void* d_ws, size_t ws_size,
                              hipStream_t stream) {
    const float* x   = (const float*)d_in[0];   // [N,128]
    const float* W1  = (const float*)d_in[1];   // [3,128,64]
    const float* b1  = (const float*)d_in[2];   // [3,64]
    const float* W2  = (const float*)d_in[3];   // [3,64,64]
    const float* b2  = (const float*)d_in[4];   // [3,64]
    const int*   src = (const int*)d_in[5];     // [3,E]
    const int*   dst = (const int*)d_in[6];     // [3,E]
    float* out = (float*)d_out;                 // [N,64]

    // workspace layout: odI | idI | cursor | offs | partials(1024) | edge_src | outnorm | innorm | A | B
    int*   odI      = (int*)d_ws;
    int*   idI      = odI + SEGS;
    int*   cursor   = idI + SEGS;
    int*   offs     = cursor + SEGS;
    int*   partials = offs + SEGS;
    int*   edge_src = partials + 1024;
    float* outnorm  = (float*)(edge_src + (size_t)RELS * NEDGE);
    float* innorm   = outnorm + SEGS;
    float* A        = innorm + SEGS;                  // [3,N,64] layer-1 h / layer-2 agg
    float* B        = A + (size_t)SEGS * FHID;        // [N,64]   layer-1 output (h1)
    // total ~62 MB

    const int EB = (NEDGE + 255) / 256;               // 2344

    // zero odI, idI, cursor (contiguous)
    hipMemsetAsync(odI, 0, 3ull * SEGS * sizeof(int), stream);

    // degrees + norms (shared by both layers)
    deg_kernel<<<dim3(EB, RELS), 256, 0, stream>>>(src, dst, odI, idI);
    norm_kernel<<<(SEGS + 255) / 256, 256, 0, stream>>>(odI, idI, outnorm, innorm);

    // CSR build on dst (shared by both layers)
    scan_sums_kernel<<<NBLK, 256, 0, stream>>>(idI, partials);
    scan_partials_kernel<<<1, 1024, 0, stream>>>(partials);
    scan_write_kernel<<<NBLK, 256, 0, stream>>>(idI, partials, offs);
    fill_kernel<<<dim3(EB, RELS), 256, 0, stream>>>(src, dst, offs, cursor, edge_src);

    // layer 1
    gemm1_kernel<<<dim3(NODES / 8, RELS), 256, 0, stream>>>(x, W1, outnorm, A);
    gather1_kernel<<<NODES / 4, 256, 0, stream>>>(A, edge_src, offs, idI, innorm, b1, B);

    // layer 2
    gather2_kernel<<<dim3(NODES / 4, RELS), 256, 0, stream>>>(B, edge_src, offs, idI, outnorm, innorm, A);
    out_kernel<<<NODES / 8, 256, 0, stream>>>(A, W2, b2, out);
}

// Round 3
// 681.658 us; speedup vs baseline: 1.9994x; 1.0749x over previous
//
#include <hip/hip_runtime.h>

#define NODES 50000
#define RELS  3
#define NEDGE 600000
#define FIN   128
#define FHID  64
#define FOUT  64
#define SEGS  (RELS * NODES)            // 150000 (rel, dst) segments
#define NBLK  ((SEGS + 255) / 256)      // 586 scan blocks

// ---------------- degree counting (int) ----------------
__global__ __launch_bounds__(256) void deg_kernel(const int* __restrict__ src,
                                                  const int* __restrict__ dst,
                                                  int* __restrict__ odI,
                                                  int* __restrict__ idI) {
    int e = blockIdx.x * 256 + threadIdx.x;
    int r = blockIdx.y;
    if (e >= NEDGE) return;
    atomicAdd(&odI[r * NODES + src[r * NEDGE + e]], 1);
    atomicAdd(&idI[r * NODES + dst[r * NEDGE + e]], 1);
}

// ---------------- norms from int degrees ----------------
__global__ __launch_bounds__(256) void norm_kernel(const int* __restrict__ odI,
                                                   const int* __restrict__ idI,
                                                   float* __restrict__ outnorm,
                                                   float* __restrict__ innorm) {
    int i = blockIdx.x * 256 + threadIdx.x;
    if (i >= SEGS) return;
    outnorm[i] = 1.0f / sqrtf(fmaxf((float)odI[i], 1.0f));
    innorm[i]  = 1.0f / sqrtf(fmaxf((float)idI[i], 1.0f));
}

// ---------------- exclusive scan over idI (3 kernels) ----------------
__global__ __launch_bounds__(256) void scan_sums_kernel(const int* __restrict__ idI,
                                                        int* __restrict__ partials) {
    __shared__ int s[256];
    int i = blockIdx.x * 256 + threadIdx.x;
    s[threadIdx.x] = (i < SEGS) ? idI[i] : 0;
    __syncthreads();
    for (int off = 128; off > 0; off >>= 1) {
        if (threadIdx.x < off) s[threadIdx.x] += s[threadIdx.x + off];
        __syncthreads();
    }
    if (threadIdx.x == 0) partials[blockIdx.x] = s[0];
}

__global__ __launch_bounds__(1024) void scan_partials_kernel(int* __restrict__ partials) {
    __shared__ int s[1024];
    int tid = threadIdx.x;
    int v = (tid < NBLK) ? partials[tid] : 0;
    s[tid] = v;
    __syncthreads();
    for (int off = 1; off < 1024; off <<= 1) {
        int t = s[tid];
        int add = (tid >= off) ? s[tid - off] : 0;
        __syncthreads();
        s[tid] = t + add;
        __syncthreads();
    }
    if (tid < NBLK) partials[tid] = s[tid] - v;   // exclusive
}

__global__ __launch_bounds__(256) void scan_write_kernel(const int* __restrict__ idI,
                                                         const int* __restrict__ partials,
                                                         int* __restrict__ offs) {
    __shared__ int s[256];
    int tid = threadIdx.x;
    int i = blockIdx.x * 256 + tid;
    int v = (i < SEGS) ? idI[i] : 0;
    s[tid] = v;
    __syncthreads();
    for (int off = 1; off < 256; off <<= 1) {
        int t = s[tid];
        int add = (tid >= off) ? s[tid - off] : 0;
        __syncthreads();
        s[tid] = t + add;
        __syncthreads();
    }
    if (i < SEGS) offs[i] = partials[blockIdx.x] + (s[tid] - v);
}

// ---------------- CSR fill: bucket src ids by (rel,dst) ----------------
__global__ __launch_bounds__(256) void fill_kernel(const int* __restrict__ src,
                                                   const int* __restrict__ dst,
                                                   const int* __restrict__ offs,
                                                   int* __restrict__ cursor,
                                                   int* __restrict__ edge_src) {
    int e = blockIdx.x * 256 + threadIdx.x;
    int r = blockIdx.y;
    if (e >= NEDGE) return;
    int seg = r * NODES + dst[r * NEDGE + e];
    int pos = offs[seg] + atomicAdd(&cursor[seg], 1);
    edge_src[pos] = src[r * NEDGE + e];
}

// ---------------- layer 1 GEMM: h[r][n][j] = (x[n,:].W1[r][:,j]) * outnorm[r][n]
// 4 rows per thread (16 rows/block), float4 x loads, W in LDS.
__global__ __launch_bounds__(256) void gemm1_kernel(const float* __restrict__ x,
                                                    const float* __restrict__ W1,
                                                    const float* __restrict__ outnorm,
                                                    float* __restrict__ h) {
    __shared__ float Wl[FIN * FHID];          // 32 KB
    int r = blockIdx.y;
    const float* Wr = W1 + r * FIN * FHID;
    for (int t = threadIdx.x; t < FIN * FHID; t += 256) Wl[t] = Wr[t];
    __syncthreads();
    int j  = threadIdx.x & 63;
    int g  = threadIdx.x >> 6;
    int n0 = blockIdx.x * 16 + g * 4;         // NODES % 16 == 0
    const float4* x0 = (const float4*)(x + (size_t)n0 * FIN);
    const float4* x1 = (const float4*)(x + (size_t)(n0 + 1) * FIN);
    const float4* x2 = (const float4*)(x + (size_t)(n0 + 2) * FIN);
    const float4* x3 = (const float4*)(x + (size_t)(n0 + 3) * FIN);
    float acc0 = 0.f, acc1 = 0.f, acc2 = 0.f, acc3 = 0.f;
#pragma unroll 8
    for (int k4 = 0; k4 < FIN / 4; ++k4) {
        float4 a0 = x0[k4], a1 = x1[k4], a2 = x2[k4], a3 = x3[k4];
        const float* w = Wl + k4 * 4 * FHID + j;
        float w0 = w[0], w1 = w[FHID], w2 = w[2 * FHID], w3 = w[3 * FHID];
        acc0 = fmaf(a0.x, w0, acc0); acc1 = fmaf(a1.x, w0, acc1);
        acc2 = fmaf(a2.x, w0, acc2); acc3 = fmaf(a3.x, w0, acc3);
        acc0 = fmaf(a0.y, w1, acc0); acc1 = fmaf(a1.y, w1, acc1);
        acc2 = fmaf(a2.y, w1, acc2); acc3 = fmaf(a3.y, w1, acc3);
        acc0 = fmaf(a0.z, w2, acc0); acc1 = fmaf(a1.z, w2, acc1);
        acc2 = fmaf(a2.z, w2, acc2); acc3 = fmaf(a3.z, w2, acc3);
        acc0 = fmaf(a0.w, w3, acc0); acc1 = fmaf(a1.w, w3, acc1);
        acc2 = fmaf(a2.w, w3, acc2); acc3 = fmaf(a3.w, w3, acc3);
    }
    size_t base = ((size_t)r * NODES + n0) * FHID + j;
    const float* on = outnorm + r * NODES + n0;
    h[base]              = acc0 * on[0];
    h[base + FHID]       = acc1 * on[1];
    h[base + 2 * FHID]   = acc2 * on[2];
    h[base + 3 * FHID]   = acc3 * on[3];
}

// ---------------- layer 1 gather ----------------
// One wave per dst node; lanes = 4 edges x 16 float4-slots. 1 KB gathered/instr.
__global__ __launch_bounds__(256) void gather1_kernel(const float* __restrict__ h,
                                                      const int* __restrict__ es,
                                                      const int* __restrict__ offs,
                                                      const int* __restrict__ cnt,
                                                      const float* __restrict__ innorm,
                                                      const float* __restrict__ b1,
                                                      float* __restrict__ B) {
    int lane = threadIdx.x & 63;
    int wv   = threadIdx.x >> 6;
    int d    = blockIdx.x * 4 + wv;           // NODES % 4 == 0
    int q    = lane & 15;                     // float4 slot within row
    int e4   = lane >> 4;                     // which of 4 edges
    float4 tot = {0.f, 0.f, 0.f, 0.f};
#pragma unroll
    for (int r = 0; r < RELS; ++r) {
        int seg = r * NODES + d;
        int o = offs[seg], c = cnt[seg];
        const float* Ar = h + (size_t)r * NODES * FHID;
        float4 s = {0.f, 0.f, 0.f, 0.f};
        int t = 0;
#pragma unroll 2
        for (; t + 4 <= c; t += 4) {
            int idx = es[o + t + e4];
            float4 v = *(const float4*)(Ar + (size_t)idx * FHID + q * 4);
            s.x += v.x; s.y += v.y; s.z += v.z; s.w += v.w;
        }
        int rem = c - t;
        if (e4 < rem) {
            int idx = es[o + t + e4];
            float4 v = *(const float4*)(Ar + (size_t)idx * FHID + q * 4);
            s.x += v.x; s.y += v.y; s.z += v.z; s.w += v.w;
        }
        float inr = innorm[seg];
        tot.x = fmaf(inr, s.x, tot.x); tot.y = fmaf(inr, s.y, tot.y);
        tot.z = fmaf(inr, s.z, tot.z); tot.w = fmaf(inr, s.w, tot.w);
    }
    // reduce across the 4 edge groups (lanes differing in bits 4,5)
    tot.x += __shfl_xor(tot.x, 16); tot.y += __shfl_xor(tot.y, 16);
    tot.z += __shfl_xor(tot.z, 16); tot.w += __shfl_xor(tot.w, 16);
    tot.x += __shfl_xor(tot.x, 32); tot.y += __shfl_xor(tot.y, 32);
    tot.z += __shfl_xor(tot.z, 32); tot.w += __shfl_xor(tot.w, 32);
    if (lane < 16) {
        float4 bs0 = ((const float4*)b1)[q];
        float4 bs1 = ((const float4*)(b1 + FHID))[q];
        float4 bs2 = ((const float4*)(b1 + 2 * FHID))[q];
        float4 o4;
        o4.x = fmaxf(tot.x + bs0.x + bs1.x + bs2.x, 0.f);
        o4.y = fmaxf(tot.y + bs0.y + bs1.y + bs2.y, 0.f);
        o4.z = fmaxf(tot.z + bs0.z + bs1.z + bs2.z, 0.f);
        o4.w = fmaxf(tot.w + bs0.w + bs1.w + bs2.w, 0.f);
        *(float4*)(B + (size_t)d * FHID + q * 4) = o4;
    }
}

// ---------------- layer 2 gather: A[r][d][j] = innorm[r][d]*sum_e outnorm[r][src]*h1[src][j]
__global__ __launch_bounds__(256) void gather2_kernel(const float* __restrict__ h1,
                                                      const int* __restrict__ es,
                                                      const int* __restrict__ offs,
                                                      const int* __restrict__ cnt,
                                                      const float* __restrict__ outnorm,
                                                      const float* __restrict__ innorm,
                                                      float* __restrict__ A) {
    int lane = threadIdx.x & 63;
    int wv   = threadIdx.x >> 6;
    int d    = blockIdx.x * 4 + wv;
    int r    = blockIdx.y;
    int q    = lane & 15;
    int e4   = lane >> 4;
    int seg = r * NODES + d;
    int o = offs[seg], c = cnt[seg];
    const float* on = outnorm + r * NODES;
    float4 s = {0.f, 0.f, 0.f, 0.f};
    int t = 0;
#pragma unroll 2
    for (; t + 4 <= c; t += 4) {
        int idx = es[o + t + e4];
        float w = on[idx];
        float4 v = *(const float4*)(h1 + (size_t)idx * FHID + q * 4);
        s.x = fmaf(w, v.x, s.x); s.y = fmaf(w, v.y, s.y);
        s.z = fmaf(w, v.z, s.z); s.w = fmaf(w, v.w, s.w);
    }
    int rem = c - t;
    if (e4 < rem) {
        int idx = es[o + t + e4];
        float w = on[idx];
        float4 v = *(const float4*)(h1 + (size_t)idx * FHID + q * 4);
        s.x = fmaf(w, v.x, s.x); s.y = fmaf(w, v.y, s.y);
        s.z = fmaf(w, v.z, s.z); s.w = fmaf(w, v.w, s.w);
    }
    s.x += __shfl_xor(s.x, 16); s.y += __shfl_xor(s.y, 16);
    s.z += __shfl_xor(s.z, 16); s.w += __shfl_xor(s.w, 16);
    s.x += __shfl_xor(s.x, 32); s.y += __shfl_xor(s.y, 32);
    s.z += __shfl_xor(s.z, 32); s.w += __shfl_xor(s.w, 32);
    if (lane < 16) {
        float inr = innorm[seg];
        float4 o4 = {inr * s.x, inr * s.y, inr * s.z, inr * s.w};
        *(float4*)(A + (size_t)seg * FHID + q * 4) = o4;
    }
}

// ---------------- layer 2 GEMM + combine: out = sum_r A[r] @ W2[r] + sum_r b2[r]
// 4 rows per thread (16 rows/block).
__global__ __launch_bounds__(256) void out_kernel(const float* __restrict__ agg2,
                                                  const float* __restrict__ W2,
                                                  const float* __restrict__ b2,
                                                  float* __restrict__ out) {
    __shared__ float Wl[RELS * FHID * FOUT];  // 48 KB
    for (int t = threadIdx.x; t < RELS * FHID * FOUT; t += 256) Wl[t] = W2[t];
    __syncthreads();
    int j  = threadIdx.x & 63;
    int g  = threadIdx.x >> 6;
    int n0 = blockIdx.x * 16 + g * 4;
    float acc0 = b2[j] + b2[FOUT + j] + b2[2 * FOUT + j];
    float acc1 = acc0, acc2 = acc0, acc3 = acc0;
#pragma unroll
    for (int r = 0; r < RELS; ++r) {
        const float4* a0 = (const float4*)(agg2 + ((size_t)r * NODES + n0) * FHID);
        const float4* a1 = (const float4*)(agg2 + ((size_t)r * NODES + n0 + 1) * FHID);
        const float4* a2 = (const float4*)(agg2 + ((size_t)r * NODES + n0 + 2) * FHID);
        const float4* a3 = (const float4*)(agg2 + ((size_t)r * NODES + n0 + 3) * FHID);
        const float* wr = Wl + r * FHID * FOUT;
#pragma unroll 4
        for (int k4 = 0; k4 < FHID / 4; ++k4) {
            float4 v0 = a0[k4], v1 = a1[k4], v2 = a2[k4], v3 = a3[k4];
            const float* w = wr + k4 * 4 * FOUT + j;
            float w0 = w[0], w1 = w[FOUT], w2 = w[2 * FOUT], w3 = w[3 * FOUT];
            acc0 = fmaf(v0.x, w0, acc0); acc1 = fmaf(v1.x, w0, acc1);
            acc2 = fmaf(v2.x, w0, acc2); acc3 = fmaf(v3.x, w0, acc3);
            acc0 = fmaf(v0.y, w1, acc0); acc1 = fmaf(v1.y, w1, acc1);
            acc2 = fmaf(v2.y, w1, acc2); acc3 = fmaf(v3.y, w1, acc3);
            acc0 = fmaf(v0.z, w2, acc0); acc1 = fmaf(v1.z, w2, acc1);
            acc2 = fmaf(v2.z, w2, acc2); acc3 = fmaf(v3.z, w2, acc3);
            acc0 = fmaf(v0.w, w3, acc0); acc1 = fmaf(v1.w, w3, acc1);
            acc2 = fmaf(v2.w, w3, acc2); acc3 = fmaf(v3.w, w3, acc3);
        }
    }
    size_t base = (size_t)n0 * FOUT + j;
    out[base]            = acc0;
    out[base + FOUT]     = acc1;
    out[base + 2 * FOUT] = acc2;
    out[base + 3 * FOUT] = acc3;
}

extern "C" void kernel_launch(void* const* d_in, const int* in_sizes, int n_in,
                              void* d_out, int out_size, void* d_ws, size_t ws_size,
                              hipStream_t stream) {
    const float* x   = (const float*)d_in[0];   // [N,128]
    const float* W1  = (const float*)d_in[1];   // [3,128,64]
    const float* b1  = (const float*)d_in[2];   // [3,64]
    const float* W2  = (const float*)d_in[3];   // [3,64,64]
    const float* b2  = (const float*)d_in[4];   // [3,64]
    const int*   src = (const int*)d_in[5];     // [3,E]
    const int*   dst = (const int*)d_in[6];     // [3,E]
    float* out = (float*)d_out;                 // [N,64]

    // workspace layout: odI | idI | cursor | offs | partials(1024) | edge_src | outnorm | innorm | A | B
    int*   odI      = (int*)d_ws;
    int*   idI      = odI + SEGS;
    int*   cursor   = idI + SEGS;
    int*   offs     = cursor + SEGS;
    int*   partials = offs + SEGS;
    int*   edge_src = partials + 1024;
    float* outnorm  = (float*)(edge_src + (size_t)RELS * NEDGE);
    float* innorm   = outnorm + SEGS;
    float* A        = innorm + SEGS;                  // [3,N,64] layer-1 h / layer-2 agg
    float* B        = A + (size_t)SEGS * FHID;        // [N,64]   layer-1 output (h1)

    const int EB = (NEDGE + 255) / 256;               // 2344

    // zero odI, idI, cursor (contiguous)
    hipMemsetAsync(odI, 0, 3ull * SEGS * sizeof(int), stream);

    // degrees + norms (shared by both layers)
    deg_kernel<<<dim3(EB, RELS), 256, 0, stream>>>(src, dst, odI, idI);
    norm_kernel<<<(SEGS + 255) / 256, 256, 0, stream>>>(odI, idI, outnorm, innorm);

    // CSR build on dst (shared by both layers)
    scan_sums_kernel<<<NBLK, 256, 0, stream>>>(idI, partials);
    scan_partials_kernel<<<1, 1024, 0, stream>>>(partials);
    scan_write_kernel<<<NBLK, 256, 0, stream>>>(idI, partials, offs);
    fill_kernel<<<dim3(EB, RELS), 256, 0, stream>>>(src, dst, offs, cursor, edge_src);

    // layer 1
    gemm1_kernel<<<dim3(NODES / 16, RELS), 256, 0, stream>>>(x, W1, outnorm, A);
    gather1_kernel<<<NODES / 4, 256, 0, stream>>>(A, edge_src, offs, idI, innorm, b1, B);

    // layer 2
    gather2_kernel<<<dim3(NODES / 4, RELS), 256, 0, stream>>>(B, edge_src, offs, idI, outnorm, innorm, A);
    out_kernel<<<NODES / 16, 256, 0, stream>>>(A, W2, b2, out);
}